// Round 9
// baseline (128.959 us; speedup 1.0000x reference)
//
#include <hip/hip_runtime.h>
#include <stdint.h>

typedef __attribute__((ext_vector_type(4))) float f32x4;
typedef __attribute__((ext_vector_type(8))) short bf16x8;

#define MFMA(a, b, c) __builtin_amdgcn_mfma_f32_16x16x32_bf16(a, b, c, 0, 0, 0)

__device__ __forceinline__ short f2b(float f) {
    uint32_t u = __builtin_bit_cast(uint32_t, f);
    u += 0x7fffu + ((u >> 16) & 1u);
    return (short)(u >> 16);
}

__device__ __forceinline__ float ex2(float x) {   // raw v_exp_f32: 2^x
    float r; asm("v_exp_f32 %0, %1" : "=v"(r) : "v"(x)); return r;
}
__device__ __forceinline__ uint32_t cvtpk(float lo, float hi) {  // 2xf32 -> packed bf16
    uint32_t r; asm("v_cvt_pk_bf16_f32 %0, %1, %2" : "=v"(r) : "v"(lo), "v"(hi)); return r;
}

typedef __attribute__((address_space(1))) const uint32_t gu32;
typedef __attribute__((address_space(3))) uint32_t su32;
__device__ __forceinline__ void stage16(const void* g, void* s) {
    // async global->LDS, 16B/lane; LDS dest = wave-uniform base + lane*16
    __builtin_amdgcn_global_load_lds((gu32*)g, (su32*)s, 16, 0, 0);
}

// bank-conflict-free slot swizzle (measured 0 conflicts since r7)
__device__ __forceinline__ int FSW(int r) { return (r & 3) | (((r >> 3) & 1) << 2); }

// Qf pre-scale: (1/sqrt(64)) * log2(e)  -> scores in log2 domain, P = 2^(S-m)
#define QSCALE 0.1803368801111601f

// ---------- fused prep: blocks 0..1023 cast W; blocks 1024..1167 transpose x
__global__ __launch_bounds__(256) void k_prep(
    const float* __restrict__ x,
    const float* __restrict__ Wq, const float* __restrict__ Wk,
    const float* __restrict__ Wv, const float* __restrict__ Wo,
    short* __restrict__ Wall, short* __restrict__ xt) {
    __shared__ float tile[64][65];
    if (blockIdx.x < 1024) {
        int idx = blockIdx.x * 256 + threadIdx.x;
        int row = idx >> 8, col = idx & 255;
        float v;
        if (row < 256)      v = Wq[row * 256 + col];
        else if (row < 512) v = Wk[(row - 256) * 256 + col];
        else if (row < 768) v = Wv[(row - 512) * 256 + col];
        else                v = Wo[(row - 768) * 256 + col];
        Wall[idx] = f2b(v);
    } else {
        int b = blockIdx.x - 1024;              // 0..143
        int pbase = (b % 36) * 64, cbase = (b / 36) * 64;
        int tx = threadIdx.x & 63, tq = threadIdx.x >> 6;
        #pragma unroll
        for (int r = 0; r < 16; r++) {
            int row = tq * 16 + r;
            tile[row][tx] = x[(cbase + row) * 2304 + pbase + tx];
        }
        __syncthreads();
        #pragma unroll
        for (int r = 0; r < 16; r++) {
            int prow = tq * 16 + r;
            xt[(pbase + prow) * 256 + cbase + tx] = f2b(tile[tx][prow]);
        }
    }
}

// ---------- QKV projection: C[768][2304] = Wall[0:768] @ x ; scatter to Qf/Kf/Vt
// Qf[n][64] bf16 (pre-scaled QSCALE), Kf[n][64] bf16, Vt[64][9216] bf16, n = p*4+h
__global__ __launch_bounds__(256) void k_gemm_qkv(
    const short* __restrict__ Wall, const short* __restrict__ xt,
    const float* __restrict__ bq, const float* __restrict__ bk, const float* __restrict__ bv,
    short* __restrict__ Qf, short* __restrict__ Kf, short* __restrict__ Vt) {
    int t = threadIdx.x, wave = t >> 6, lane = t & 63, lr = lane & 15, lg = lane >> 4;
    int obase = blockIdx.x * 64 + wave * 16;   // grid.x = 12
    int pbase = blockIdx.y * 64;               // grid.y = 36
    const short* arow  = Wall + (obase + lr) * 256 + lg * 8;
    const short* brow0 = xt + (pbase +  0 + lr) * 256 + lg * 8;
    const short* brow1 = xt + (pbase + 16 + lr) * 256 + lg * 8;
    const short* brow2 = xt + (pbase + 32 + lr) * 256 + lg * 8;
    const short* brow3 = xt + (pbase + 48 + lr) * 256 + lg * 8;
    f32x4 acc0 = {0,0,0,0}, acc1 = {0,0,0,0}, acc2 = {0,0,0,0}, acc3 = {0,0,0,0};
    #pragma unroll
    for (int ks = 0; ks < 8; ks++) {
        bf16x8 a = *(const bf16x8*)(arow + ks * 32);
        acc0 = MFMA(a, *(const bf16x8*)(brow0 + ks * 32), acc0);
        acc1 = MFMA(a, *(const bf16x8*)(brow1 + ks * 32), acc1);
        acc2 = MFMA(a, *(const bf16x8*)(brow2 + ks * 32), acc2);
        acc3 = MFMA(a, *(const bf16x8*)(brow3 + ks * 32), acc3);
    }
    int w_idx = obase >> 8;  // 0=q 1=k 2=v, uniform per block
    const float* bias = (w_idx == 0) ? bq : (w_idx == 1) ? bk : bv;
    f32x4 accs[4] = {acc0, acc1, acc2, acc3};
    #pragma unroll
    for (int i = 0; i < 4; i++) {
        int o = obase + 4 * lg + i;
        int oo = o & 255;
        float b = bias[oo];
        int h = oo >> 6, d = oo & 63;
        #pragma unroll
        for (int ct = 0; ct < 4; ct++) {
            int p = pbase + ct * 16 + lr;
            float val = accs[ct][i] + b;
            int n = p * 4 + h;
            if (w_idx == 0)      Qf[n * 64 + d] = f2b(val * QSCALE);
            else if (w_idx == 1) Kf[n * 64 + d] = f2b(val);
            else                 Vt[d * 9216 + n] = f2b(val);
        }
    }
}

// ---------- flash attention: N=9216, d=64. Grid (144 qblocks, nsplit kvchunks).
// Block = 4 waves x 256 thr = 64 queries (wave owns 16; r7's best shape).
// K staged in LDS (global_load_lds, double-buffered, FSW swizzle, 16KB/block);
// V streamed from GLOBAL: the 4 waves read the same 8KB V tile inside one
// barrier window -> L1 serves the re-reads; V loads issued before the K
// ds_reads so their L2 latency hides under the softmax VALU phase.
// QK accumulator C-initialized with -m (cin) => MFMA emits S-m directly, no
// per-score subtract. Log2-domain softmax, defer-max THR=11 (rescale branch
// folds the adjustment), cvt_pk P-pack, ones-MFMA denominator.
// Swapped QK^T (mfma(K,Q)=S^T, perm'd rows) => st regs are the PV B-frag.
__global__ __launch_bounds__(256) void k_attn(
    const short* __restrict__ Qf, const short* __restrict__ Kf,
    const short* __restrict__ Vt, int keysPer, int ntiles,
    float* __restrict__ pm, float* __restrict__ ps, float* __restrict__ pacc) {
    __shared__ short ktile[2][4096];   // [buf][64 keys][64 d], slot-swizzled
    int t = threadIdx.x, wave = t >> 6, lane = t & 63, lr = lane & 15, lg = lane >> 4;
    int kb = blockIdx.y;
    int qbase = blockIdx.x * 64 + wave * 16;   // grid.x = 144
    int kstart = kb * keysPer;

    const short* qrow = Qf + (qbase + lr) * 64 + lg * 8;
    bf16x8 q0 = *(const bf16x8*)(qrow);
    bf16x8 q1 = *(const bf16x8*)(qrow + 32);

    bf16x8 ones;
    #pragma unroll
    for (int i = 0; i < 8; i++) ones[i] = (short)0x3F80;   // bf16 1.0

    // ---- K staging: wave stages rows wave*16..+15 (2 calls x 8 rows)
    int sr = lane >> 3, slot = lane & 7;
    int colE = (slot ^ (sr & 3)) << 4;         // FSW(wave*16+sr)    = sr&3
    int colO = (slot ^ ((sr & 3) | 4)) << 4;   // FSW(wave*16+8+sr) = (sr&3)|4
    const char* kS0 = (const char*)Kf + (size_t)(kstart + wave * 16 + sr) * 128 + colE;
    const char* kS1 = (const char*)Kf + (size_t)(kstart + wave * 16 + 8 + sr) * 128 + colO;
    short* kD0[2] = { &ktile[0][wave * 1024], &ktile[1][wave * 1024] };
    short* kD1[2] = { kD0[0] + 512, kD0[1] + 512 };

    // ---- K ds_read byte offsets (tile-relative; FSW on read side)
    int perm = (lr & 3) + 8 * (lr >> 2);   // K-row perm: st regs -> keys 8*lg+i
    int cb = lg * 16;
    int kOffA0 = perm * 128       + (cb        ^ (FSW(perm) << 4));
    int kOffA1 = perm * 128       + ((cb + 64) ^ (FSW(perm) << 4));
    int kOffB0 = (perm + 4) * 128 + (cb        ^ (FSW(perm + 4) << 4));
    int kOffB1 = (perm + 4) * 128 + ((cb + 64) ^ (FSW(perm + 4) << 4));

    // ---- V global base: lane reads V[dv = lr+16m][k = jb + lg*8 (+32)]
    const short* vg = Vt + (size_t)lr * 9216 + kstart + lg * 8;

    float mA = 0.f;                        // running max (log2 domain), rel. 0
    f32x4 zv = {0,0,0,0};
    f32x4 cin = zv;                        // QK C-init = -mA (splat)
    f32x4 acc0 = zv, acc1 = zv, acc2 = zv, acc3 = zv, sacc = zv;

    // prologue: stage tile 0 into buf 0
    stage16(kS0, kD0[0]); stage16(kS1, kD1[0]);

    for (int tt = 0; tt < ntiles; tt++) {
        __syncthreads();                 // drain -> K tile tt staged, all waves
        int buf = tt & 1;
        if (tt + 1 < ntiles) {
            size_t ko = (size_t)(tt + 1) * 8192;
            stage16(kS0 + ko, kD0[buf ^ 1]);
            stage16(kS1 + ko, kD1[buf ^ 1]);
        }
        // ---- issue V loads early (consumed after softmax; L2 latency hidden)
        const short* vp = vg + tt * 64;
        bf16x8 v0a = *(const bf16x8*)(vp);
        bf16x8 v0b = *(const bf16x8*)(vp + 32);
        bf16x8 v1a = *(const bf16x8*)(vp + 147456);
        bf16x8 v1b = *(const bf16x8*)(vp + 147456 + 32);
        bf16x8 v2a = *(const bf16x8*)(vp + 294912);
        bf16x8 v2b = *(const bf16x8*)(vp + 294912 + 32);
        bf16x8 v3a = *(const bf16x8*)(vp + 442368);
        bf16x8 v3b = *(const bf16x8*)(vp + 442368 + 32);

        const char* kt = (const char*)&ktile[buf][0];
        // ---- QK^T (S^T) with C = -m: st = S - mA directly
        bf16x8 kA0 = *(const bf16x8*)(kt + kOffA0);
        bf16x8 kA1 = *(const bf16x8*)(kt + kOffA1);
        bf16x8 kB0 = *(const bf16x8*)(kt + kOffB0);
        bf16x8 kB1 = *(const bf16x8*)(kt + kOffB1);
        f32x4 st0 = MFMA(kA0, q0, cin); st0 = MFMA(kA1, q1, st0);
        f32x4 st1 = MFMA(kB0, q0, cin); st1 = MFMA(kB1, q1, st1);
        bf16x8 kC0 = *(const bf16x8*)(kt + 4096 + kOffA0);
        bf16x8 kC1 = *(const bf16x8*)(kt + 4096 + kOffA1);
        bf16x8 kE0 = *(const bf16x8*)(kt + 4096 + kOffB0);
        bf16x8 kE1 = *(const bf16x8*)(kt + 4096 + kOffB1);
        f32x4 st2 = MFMA(kC0, q0, cin); st2 = MFMA(kC1, q1, st2);
        f32x4 st3 = MFMA(kE0, q0, cin); st3 = MFMA(kE1, q1, st3);

        // ---- 64-key max of (S - mA) per query (4-lane reduce)
        float tm = fmaxf(
            fmaxf(fmaxf(fmaxf(st0[0], st0[1]), fmaxf(st0[2], st0[3])),
                  fmaxf(fmaxf(st1[0], st1[1]), fmaxf(st1[2], st1[3]))),
            fmaxf(fmaxf(fmaxf(st2[0], st2[1]), fmaxf(st2[2], st2[3])),
                  fmaxf(fmaxf(st3[0], st3[1]), fmaxf(st3[2], st3[3]))));
        tm = fmaxf(fmaxf(tm, __shfl_xor(tm, 16)),
                   fmaxf(__shfl_xor(tm, 32), __shfl_xor(tm, 48)));
        if (!__all(tm <= 11.0f)) {         // defer-max: rescale rarely
            float mn = fmaxf(tm, 0.f);
            float sc = ex2(-mn);
            acc0 *= sc; acc1 *= sc; acc2 *= sc; acc3 *= sc; sacc *= sc;
            mA += mn;
            f32x4 mnv = {mn, mn, mn, mn};
            cin -= mnv;
            st0 -= mnv; st1 -= mnv; st2 -= mnv; st3 -= mnv;
        }
        union { uint32_t w[4]; bf16x8 v; } pa, pb;
        pa.w[0] = cvtpk(ex2(st0[0]), ex2(st0[1]));
        pa.w[1] = cvtpk(ex2(st0[2]), ex2(st0[3]));
        pa.w[2] = cvtpk(ex2(st1[0]), ex2(st1[1]));
        pa.w[3] = cvtpk(ex2(st1[2]), ex2(st1[3]));
        pb.w[0] = cvtpk(ex2(st2[0]), ex2(st2[1]));
        pb.w[1] = cvtpk(ex2(st2[2]), ex2(st2[3]));
        pb.w[2] = cvtpk(ex2(st3[0]), ex2(st3[1]));
        pb.w[3] = cvtpk(ex2(st3[2]), ex2(st3[3]));

        // ---- PV over both key halves + denominator
        acc0 = MFMA(v0a, pa.v, acc0); acc0 = MFMA(v0b, pb.v, acc0);
        acc1 = MFMA(v1a, pa.v, acc1); acc1 = MFMA(v1b, pb.v, acc1);
        acc2 = MFMA(v2a, pa.v, acc2); acc2 = MFMA(v2b, pb.v, acc2);
        acc3 = MFMA(v3a, pa.v, acc3); acc3 = MFMA(v3b, pb.v, acc3);
        sacc = MFMA(ones, pa.v, sacc); sacc = MFMA(ones, pb.v, sacc);
    }

    // ---- per-wave partial out
    int g = blockIdx.x * 4 + wave;       // 0..575 global 16-query group
    int pidx = kb * 576 + g;
    float* pa_ = pacc + (size_t)pidx * 1024 + lr * 64 + lg * 4;
    *(f32x4*)(pa_ +  0) = acc0;
    *(f32x4*)(pa_ + 16) = acc1;
    *(f32x4*)(pa_ + 32) = acc2;
    *(f32x4*)(pa_ + 48) = acc3;
    if (lg == 0) {                       // sacc[0] = s[q=lr]
        pm[pidx * 16 + lr] = mA;
        ps[pidx * 16 + lr] = sacc[0];
    }
}

// ---------- combine nsplit KV-chunk partials -> Of bf16 [2304][256]
__global__ __launch_bounds__(256) void k_attn_combine(
    const float* __restrict__ pm, const float* __restrict__ ps,
    const float* __restrict__ pacc, short* __restrict__ Of, int nsplit) {
    int qb = blockIdx.x, t = threadIdx.x;   // grid = 576; thread owns one f32x4
    int q = t >> 4, dv4 = (t & 15) * 4;
    float mg = -1e30f;
    for (int s = 0; s < nsplit; s++)
        mg = fmaxf(mg, pm[(s * 576 + qb) * 16 + q]);
    float S = 0.f;
    f32x4 O = {0, 0, 0, 0};
    for (int s = 0; s < nsplit; s++) {
        float e = ex2(pm[(s * 576 + qb) * 16 + q] - mg);   // log2 domain
        S += ps[(s * 576 + qb) * 16 + q] * e;
        f32x4 pv = *(const f32x4*)(pacc + (size_t)(s * 576 + qb) * 1024 + q * 64 + dv4);
        O += pv * e;
    }
    float inv = 1.0f / S;
    uint32_t w0 = cvtpk(O[0] * inv, O[1] * inv);
    uint32_t w1 = cvtpk(O[2] * inv, O[3] * inv);
    int n = qb * 16 + q, p = n >> 2, hh = n & 3;
    uint2 pk; pk.x = w0; pk.y = w1;
    *(uint2*)(&Of[p * 256 + hh * 64 + dv4]) = pk;
}

// ---------- output projection: out[256][2304] = Wo @ Of^T + bo (fp32 out, NCHW)
__global__ __launch_bounds__(256) void k_gemm_out(
    const short* __restrict__ Wo_bf, const short* __restrict__ Of,
    const float* __restrict__ bo, float* __restrict__ out) {
    int t = threadIdx.x, wave = t >> 6, lane = t & 63, lr = lane & 15, lg = lane >> 4;
    int obase = blockIdx.x * 64 + wave * 16;   // grid.x = 4
    int pbase = blockIdx.y * 64;               // grid.y = 36
    const short* arow  = Wo_bf + (obase + lr) * 256 + lg * 8;
    const short* brow0 = Of + (pbase +  0 + lr) * 256 + lg * 8;
    const short* brow1 = Of + (pbase + 16 + lr) * 256 + lg * 8;
    const short* brow2 = Of + (pbase + 32 + lr) * 256 + lg * 8;
    const short* brow3 = Of + (pbase + 48 + lr) * 256 + lg * 8;
    f32x4 acc0 = {0,0,0,0}, acc1 = {0,0,0,0}, acc2 = {0,0,0,0}, acc3 = {0,0,0,0};
    #pragma unroll
    for (int ks = 0; ks < 8; ks++) {
        bf16x8 a = *(const bf16x8*)(arow + ks * 32);
        acc0 = MFMA(a, *(const bf16x8*)(brow0 + ks * 32), acc0);
        acc1 = MFMA(a, *(const bf16x8*)(brow1 + ks * 32), acc1);
        acc2 = MFMA(a, *(const bf16x8*)(brow2 + ks * 32), acc2);
        acc3 = MFMA(a, *(const bf16x8*)(brow3 + ks * 32), acc3);
    }
    f32x4 accs[4] = {acc0, acc1, acc2, acc3};
    #pragma unroll
    for (int i = 0; i < 4; i++) {
        int o = obase + 4 * lg + i;
        float b = bo[o];
        #pragma unroll
        for (int ct = 0; ct < 4; ct++) {
            int p = pbase + ct * 16 + lr;
            out[o * 2304 + p] = accs[ct][i] + b;
        }
    }
}

extern "C" void kernel_launch(void* const* d_in, const int* in_sizes, int n_in,
                              void* d_out, int out_size, void* d_ws, size_t ws_size,
                              hipStream_t stream) {
    const float* x  = (const float*)d_in[0];
    const float* Wq = (const float*)d_in[1];
    const float* bq = (const float*)d_in[2];
    const float* Wk = (const float*)d_in[3];
    const float* bk = (const float*)d_in[4];
    const float* Wv = (const float*)d_in[5];
    const float* bv = (const float*)d_in[6];
    const float* Wo = (const float*)d_in[7];
    const float* bo = (const float*)d_in[8];

    char* ws = (char*)d_ws;
    short* Wall = (short*)(ws);                     // 1024*256*2 = 524288 B
    short* xt   = (short*)(ws + 524288);            // 2304*256*2
    short* Qf   = (short*)(ws + 1703936);           // 9216*64*2
    short* Kf   = (short*)(ws + 2883584);           // 9216*64*2
    short* Vt   = (short*)(ws + 4063232);           // 64*9216*2
    short* Of   = (short*)(ws + 5242880);           // 2304*256*2 (ends 6422528)
    float* pm   = (float*)(ws + 6422528);           // 8*576*16*4 = 294912 max
    float* ps   = (float*)(ws + 6717440);           // 294912 max
    float* pacc = (float*)(ws + 7012352);           // nsplit*576*1024*4
    float* out  = (float*)d_out;

    // nsplit=8 needs ws end ~25.9MB; fall back to 4 (16.4MB) if ws is small
    int nsplit = (ws_size >= (size_t)7012352 + 8u * 2359296u) ? 8 : 4;
    int keysPer = 9216 / nsplit;
    int ntiles = keysPer / 64;

    k_prep<<<1168, 256, 0, stream>>>(x, Wq, Wk, Wv, Wo, Wall, xt);
    k_gemm_qkv<<<dim3(12, 36), 256, 0, stream>>>(Wall, xt, bq, bk, bv, Qf, Kf, Vt);
    k_attn<<<dim3(144, nsplit), 256, 0, stream>>>(Qf, Kf, Vt, keysPer, ntiles, pm, ps, pacc);
    k_attn_combine<<<576, 256, 0, stream>>>(pm, ps, pacc, Of, nsplit);
    k_gemm_out<<<dim3(4, 36), 256, 0, stream>>>(Wall + 768 * 256, Of, bo, out);
}

// Round 10
// 80.346 us; speedup vs baseline: 1.6050x; 1.6050x over previous
//
#include <hip/hip_runtime.h>
#include <stdint.h>

typedef __attribute__((ext_vector_type(4))) float f32x4;
typedef __attribute__((ext_vector_type(8))) short bf16x8;

#define MFMA(a, b, c) __builtin_amdgcn_mfma_f32_16x16x32_bf16(a, b, c, 0, 0, 0)

__device__ __forceinline__ short f2b(float f) {
    uint32_t u = __builtin_bit_cast(uint32_t, f);
    u += 0x7fffu + ((u >> 16) & 1u);
    return (short)(u >> 16);
}

__device__ __forceinline__ float ex2(float x) {   // raw v_exp_f32: 2^x
    float r; asm("v_exp_f32 %0, %1" : "=v"(r) : "v"(x)); return r;
}
__device__ __forceinline__ uint32_t cvtpk(float lo, float hi) {  // 2xf32 -> packed bf16
    uint32_t r; asm("v_cvt_pk_bf16_f32 %0, %1, %2" : "=v"(r) : "v"(lo), "v"(hi)); return r;
}

typedef __attribute__((address_space(1))) const uint32_t gu32;
typedef __attribute__((address_space(3))) uint32_t su32;
__device__ __forceinline__ void stage16(const void* g, void* s) {
    // async global->LDS, 16B/lane; LDS dest = wave-uniform base + lane*16
    __builtin_amdgcn_global_load_lds((gu32*)g, (su32*)s, 16, 0, 0);
}

// bank-conflict-free slot swizzle (measured 0 conflicts since r7)
__device__ __forceinline__ int FSW(int r) { return (r & 3) | (((r >> 3) & 1) << 2); }

// Qf pre-scale: (1/sqrt(64)) * log2(e)  -> scores in log2 domain, P = 2^(S-m)
#define QSCALE 0.1803368801111601f

// ---------- fused prep: blocks 0..1023 cast W; blocks 1024..1167 transpose x
__global__ __launch_bounds__(256) void k_prep(
    const float* __restrict__ x,
    const float* __restrict__ Wq, const float* __restrict__ Wk,
    const float* __restrict__ Wv, const float* __restrict__ Wo,
    short* __restrict__ Wall, short* __restrict__ xt) {
    __shared__ float tile[64][65];
    if (blockIdx.x < 1024) {
        int idx = blockIdx.x * 256 + threadIdx.x;
        int row = idx >> 8, col = idx & 255;
        float v;
        if (row < 256)      v = Wq[row * 256 + col];
        else if (row < 512) v = Wk[(row - 256) * 256 + col];
        else if (row < 768) v = Wv[(row - 512) * 256 + col];
        else                v = Wo[(row - 768) * 256 + col];
        Wall[idx] = f2b(v);
    } else {
        int b = blockIdx.x - 1024;              // 0..143
        int pbase = (b % 36) * 64, cbase = (b / 36) * 64;
        int tx = threadIdx.x & 63, tq = threadIdx.x >> 6;
        #pragma unroll
        for (int r = 0; r < 16; r++) {
            int row = tq * 16 + r;
            tile[row][tx] = x[(cbase + row) * 2304 + pbase + tx];
        }
        __syncthreads();
        #pragma unroll
        for (int r = 0; r < 16; r++) {
            int prow = tq * 16 + r;
            xt[(pbase + prow) * 256 + cbase + tx] = f2b(tile[tx][prow]);
        }
    }
}

// ---------- QKV projection: C[768][2304] = Wall[0:768] @ x ; scatter to Qf/Kf/Vt
// Qf[n][64] bf16 (pre-scaled QSCALE), Kf[n][64] bf16, Vt[64][9216] bf16, n = p*4+h
__global__ __launch_bounds__(256) void k_gemm_qkv(
    const short* __restrict__ Wall, const short* __restrict__ xt,
    const float* __restrict__ bq, const float* __restrict__ bk, const float* __restrict__ bv,
    short* __restrict__ Qf, short* __restrict__ Kf, short* __restrict__ Vt) {
    int t = threadIdx.x, wave = t >> 6, lane = t & 63, lr = lane & 15, lg = lane >> 4;
    int obase = blockIdx.x * 64 + wave * 16;   // grid.x = 12
    int pbase = blockIdx.y * 64;               // grid.y = 36
    const short* arow  = Wall + (obase + lr) * 256 + lg * 8;
    const short* brow0 = xt + (pbase +  0 + lr) * 256 + lg * 8;
    const short* brow1 = xt + (pbase + 16 + lr) * 256 + lg * 8;
    const short* brow2 = xt + (pbase + 32 + lr) * 256 + lg * 8;
    const short* brow3 = xt + (pbase + 48 + lr) * 256 + lg * 8;
    f32x4 acc0 = {0,0,0,0}, acc1 = {0,0,0,0}, acc2 = {0,0,0,0}, acc3 = {0,0,0,0};
    #pragma unroll
    for (int ks = 0; ks < 8; ks++) {
        bf16x8 a = *(const bf16x8*)(arow + ks * 32);
        acc0 = MFMA(a, *(const bf16x8*)(brow0 + ks * 32), acc0);
        acc1 = MFMA(a, *(const bf16x8*)(brow1 + ks * 32), acc1);
        acc2 = MFMA(a, *(const bf16x8*)(brow2 + ks * 32), acc2);
        acc3 = MFMA(a, *(const bf16x8*)(brow3 + ks * 32), acc3);
    }
    int w_idx = obase >> 8;  // 0=q 1=k 2=v, uniform per block
    const float* bias = (w_idx == 0) ? bq : (w_idx == 1) ? bk : bv;
    f32x4 accs[4] = {acc0, acc1, acc2, acc3};
    #pragma unroll
    for (int i = 0; i < 4; i++) {
        int o = obase + 4 * lg + i;
        int oo = o & 255;
        float b = bias[oo];
        int h = oo >> 6, d = oo & 63;
        #pragma unroll
        for (int ct = 0; ct < 4; ct++) {
            int p = pbase + ct * 16 + lr;
            float val = accs[ct][i] + b;
            int n = p * 4 + h;
            if (w_idx == 0)      Qf[n * 64 + d] = f2b(val * QSCALE);
            else if (w_idx == 1) Kf[n * 64 + d] = f2b(val);
            else                 Vt[d * 9216 + n] = f2b(val);
        }
    }
}

// ---------- flash attention: N=9216, d=64. Grid (144 qblocks, nsplit kvchunks).
// r7 structure (measured 48us, 0 bank conflicts): block = 4 waves x 256 thr =
// 64 queries (wave owns 16). K [64][64] AND V [64dv][64k] staged via
// global_load_lds (double-buffered, FSW slot-swizzle both sides). RULE (r1-r5,
// r9, 3x verified): every MFMA operand arrives via LDS staging; per-wave
// global streams serialize into latency chains regardless of cache residency.
// + r9's C-init=-m: QK accumulator initialized with -m so MFMA emits S-m
// directly (no per-score subtract); defer-max THR=11 rescale folds the shift.
// Log2-domain softmax (Qf pre-scaled QSCALE), cvt_pk P-pack, ones-MFMA denom.
// Swapped QK^T (mfma(K,Q)=S^T, perm'd rows) => st regs are the PV B-frag.
__global__ __launch_bounds__(256) void k_attn(
    const short* __restrict__ Qf, const short* __restrict__ Kf,
    const short* __restrict__ Vt, int keysPer, int ntiles,
    float* __restrict__ pm, float* __restrict__ ps, float* __restrict__ pacc) {
    __shared__ short ktile[2][4096];   // [buf][64 keys][64 d], slot-swizzled
    __shared__ short vtile[2][4096];   // [buf][64 dv][64 keys], slot-swizzled
    int t = threadIdx.x, wave = t >> 6, lane = t & 63, lr = lane & 15, lg = lane >> 4;
    int kb = blockIdx.y;
    int qbase = blockIdx.x * 64 + wave * 16;   // grid.x = 144
    int kstart = kb * keysPer;

    const short* qrow = Qf + (qbase + lr) * 64 + lg * 8;
    bf16x8 q0 = *(const bf16x8*)(qrow);
    bf16x8 q1 = *(const bf16x8*)(qrow + 32);

    bf16x8 ones;
    #pragma unroll
    for (int i = 0; i < 8; i++) ones[i] = (short)0x3F80;   // bf16 1.0

    // ---- staging: wave stages 16 rows of K and V (2 calls x 8 rows each)
    int sr = lane >> 3, slot = lane & 7;
    int srow0 = wave * 16 + sr, srow1 = srow0 + 8;
    int col0 = (slot ^ FSW(srow0)) << 4;      // pre-swizzled global byte col
    int col1 = (slot ^ FSW(srow1)) << 4;
    const char* kS0 = (const char*)Kf + (size_t)(kstart + srow0) * 128 + col0;
    const char* kS1 = (const char*)Kf + (size_t)(kstart + srow1) * 128 + col1;
    const char* vS0 = (const char*)Vt + (size_t)srow0 * 18432 + (size_t)kstart * 2 + col0;
    const char* vS1 = (const char*)Vt + (size_t)srow1 * 18432 + (size_t)kstart * 2 + col1;
    short* kD0[2] = { &ktile[0][wave * 1024], &ktile[1][wave * 1024] };
    short* kD1[2] = { kD0[0] + 512, kD0[1] + 512 };
    short* vD0[2] = { &vtile[0][wave * 1024], &vtile[1][wave * 1024] };
    short* vD1[2] = { vD0[0] + 512, vD0[1] + 512 };

    // ---- ds_read byte offsets (tile-relative; FSW applied on read side)
    int perm = (lr & 3) + 8 * (lr >> 2);   // K-row perm: st regs -> keys 8*lg+i
    int cb = lg * 16;
    int kOffA0 = perm * 128       + (cb        ^ (FSW(perm) << 4));
    int kOffA1 = perm * 128       + ((cb + 64) ^ (FSW(perm) << 4));
    int kOffB0 = (perm + 4) * 128 + (cb        ^ (FSW(perm + 4) << 4));
    int kOffB1 = (perm + 4) * 128 + ((cb + 64) ^ (FSW(perm + 4) << 4));
    int vOff   = lr * 128         + (cb        ^ (FSW(lr) << 4));
    // V rows lr+16k share FSW(lr); +16 rows = +2048B. 2nd key-half = ^64.

    float mA = 0.f;                        // running max (log2 domain), rel. 0
    f32x4 zv = {0,0,0,0};
    f32x4 cin = zv;                        // QK C-init = -mA (splat)
    f32x4 acc0 = zv, acc1 = zv, acc2 = zv, acc3 = zv, sacc = zv;

    // prologue: stage tile 0 into buf 0
    stage16(kS0, kD0[0]); stage16(kS1, kD1[0]);
    stage16(vS0, vD0[0]); stage16(vS1, vD1[0]);

    for (int tt = 0; tt < ntiles; tt++) {
        __syncthreads();                 // drain -> tile tt staged for all waves
        int buf = tt & 1;
        if (tt + 1 < ntiles) {
            size_t ko = (size_t)(tt + 1) * 8192, vo = (size_t)(tt + 1) * 128;
            stage16(kS0 + ko, kD0[buf ^ 1]); stage16(kS1 + ko, kD1[buf ^ 1]);
            stage16(vS0 + vo, vD0[buf ^ 1]); stage16(vS1 + vo, vD1[buf ^ 1]);
        }
        const char* kt = (const char*)&ktile[buf][0];
        const char* vt = (const char*)&vtile[buf][0];

        // ---- QK^T (S^T) with C = -m: st = S - mA directly
        bf16x8 kA0 = *(const bf16x8*)(kt + kOffA0);
        bf16x8 kA1 = *(const bf16x8*)(kt + kOffA1);
        bf16x8 kB0 = *(const bf16x8*)(kt + kOffB0);
        bf16x8 kB1 = *(const bf16x8*)(kt + kOffB1);
        f32x4 st0 = MFMA(kA0, q0, cin); st0 = MFMA(kA1, q1, st0);
        f32x4 st1 = MFMA(kB0, q0, cin); st1 = MFMA(kB1, q1, st1);
        bf16x8 kC0 = *(const bf16x8*)(kt + 4096 + kOffA0);
        bf16x8 kC1 = *(const bf16x8*)(kt + 4096 + kOffA1);
        bf16x8 kE0 = *(const bf16x8*)(kt + 4096 + kOffB0);
        bf16x8 kE1 = *(const bf16x8*)(kt + 4096 + kOffB1);
        f32x4 st2 = MFMA(kC0, q0, cin); st2 = MFMA(kC1, q1, st2);
        f32x4 st3 = MFMA(kE0, q0, cin); st3 = MFMA(kE1, q1, st3);

        // ---- merged 64-key max of (S - mA) per query
        float tm = fmaxf(
            fmaxf(fmaxf(fmaxf(st0[0], st0[1]), fmaxf(st0[2], st0[3])),
                  fmaxf(fmaxf(st1[0], st1[1]), fmaxf(st1[2], st1[3]))),
            fmaxf(fmaxf(fmaxf(st2[0], st2[1]), fmaxf(st2[2], st2[3])),
                  fmaxf(fmaxf(st3[0], st3[1]), fmaxf(st3[2], st3[3]))));
        tm = fmaxf(fmaxf(tm, __shfl_xor(tm, 16)),
                   fmaxf(__shfl_xor(tm, 32), __shfl_xor(tm, 48)));
        if (!__all(tm <= 11.0f)) {         // defer-max: rescale rarely
            float mn = fmaxf(tm, 0.f);
            float sc = ex2(-mn);
            acc0 *= sc; acc1 *= sc; acc2 *= sc; acc3 *= sc; sacc *= sc;
            mA += mn;
            f32x4 mnv = {mn, mn, mn, mn};
            cin -= mnv;
            st0 -= mnv; st1 -= mnv; st2 -= mnv; st3 -= mnv;
        }
        union { uint32_t w[4]; bf16x8 v; } pa, pb;
        pa.w[0] = cvtpk(ex2(st0[0]), ex2(st0[1]));
        pa.w[1] = cvtpk(ex2(st0[2]), ex2(st0[3]));
        pa.w[2] = cvtpk(ex2(st1[0]), ex2(st1[1]));
        pa.w[3] = cvtpk(ex2(st1[2]), ex2(st1[3]));
        pb.w[0] = cvtpk(ex2(st2[0]), ex2(st2[1]));
        pb.w[1] = cvtpk(ex2(st2[2]), ex2(st2[3]));
        pb.w[2] = cvtpk(ex2(st3[0]), ex2(st3[1]));
        pb.w[3] = cvtpk(ex2(st3[2]), ex2(st3[3]));

        // ---- PV over both key halves + denominator
        bf16x8 v0a = *(const bf16x8*)(vt + vOff);
        bf16x8 v0b = *(const bf16x8*)(vt + (vOff ^ 64));
        bf16x8 v1a = *(const bf16x8*)(vt + vOff + 2048);
        bf16x8 v1b = *(const bf16x8*)(vt + ((vOff + 2048) ^ 64));
        bf16x8 v2a = *(const bf16x8*)(vt + vOff + 4096);
        bf16x8 v2b = *(const bf16x8*)(vt + ((vOff + 4096) ^ 64));
        bf16x8 v3a = *(const bf16x8*)(vt + vOff + 6144);
        bf16x8 v3b = *(const bf16x8*)(vt + ((vOff + 6144) ^ 64));
        acc0 = MFMA(v0a, pa.v, acc0); acc0 = MFMA(v0b, pb.v, acc0);
        acc1 = MFMA(v1a, pa.v, acc1); acc1 = MFMA(v1b, pb.v, acc1);
        acc2 = MFMA(v2a, pa.v, acc2); acc2 = MFMA(v2b, pb.v, acc2);
        acc3 = MFMA(v3a, pa.v, acc3); acc3 = MFMA(v3b, pb.v, acc3);
        sacc = MFMA(ones, pa.v, sacc); sacc = MFMA(ones, pb.v, sacc);
    }

    // ---- per-wave partial out
    int g = blockIdx.x * 4 + wave;       // 0..575 global 16-query group
    int pidx = kb * 576 + g;
    float* pa_ = pacc + (size_t)pidx * 1024 + lr * 64 + lg * 4;
    *(f32x4*)(pa_ +  0) = acc0;
    *(f32x4*)(pa_ + 16) = acc1;
    *(f32x4*)(pa_ + 32) = acc2;
    *(f32x4*)(pa_ + 48) = acc3;
    if (lg == 0) {                       // sacc[0] = s[q=lr]
        pm[pidx * 16 + lr] = mA;
        ps[pidx * 16 + lr] = sacc[0];
    }
}

// ---------- combine nsplit KV-chunk partials -> Of bf16 [2304][256]
__global__ __launch_bounds__(256) void k_attn_combine(
    const float* __restrict__ pm, const float* __restrict__ ps,
    const float* __restrict__ pacc, short* __restrict__ Of, int nsplit) {
    int qb = blockIdx.x, t = threadIdx.x;   // grid = 576; thread owns one f32x4
    int q = t >> 4, dv4 = (t & 15) * 4;
    float mg = -1e30f;
    for (int s = 0; s < nsplit; s++)
        mg = fmaxf(mg, pm[(s * 576 + qb) * 16 + q]);
    float S = 0.f;
    f32x4 O = {0, 0, 0, 0};
    for (int s = 0; s < nsplit; s++) {
        float e = ex2(pm[(s * 576 + qb) * 16 + q] - mg);   // log2 domain
        S += ps[(s * 576 + qb) * 16 + q] * e;
        f32x4 pv = *(const f32x4*)(pacc + (size_t)(s * 576 + qb) * 1024 + q * 64 + dv4);
        O += pv * e;
    }
    float inv = 1.0f / S;
    uint32_t w0 = cvtpk(O[0] * inv, O[1] * inv);
    uint32_t w1 = cvtpk(O[2] * inv, O[3] * inv);
    int n = qb * 16 + q, p = n >> 2, hh = n & 3;
    uint2 pk; pk.x = w0; pk.y = w1;
    *(uint2*)(&Of[p * 256 + hh * 64 + dv4]) = pk;
}

// ---------- output projection: out[256][2304] = Wo @ Of^T + bo (fp32 out, NCHW)
__global__ __launch_bounds__(256) void k_gemm_out(
    const short* __restrict__ Wo_bf, const short* __restrict__ Of,
    const float* __restrict__ bo, float* __restrict__ out) {
    int t = threadIdx.x, wave = t >> 6, lane = t & 63, lr = lane & 15, lg = lane >> 4;
    int obase = blockIdx.x * 64 + wave * 16;   // grid.x = 4
    int pbase = blockIdx.y * 64;               // grid.y = 36
    const short* arow  = Wo_bf + (obase + lr) * 256 + lg * 8;
    const short* brow0 = Of + (pbase +  0 + lr) * 256 + lg * 8;
    const short* brow1 = Of + (pbase + 16 + lr) * 256 + lg * 8;
    const short* brow2 = Of + (pbase + 32 + lr) * 256 + lg * 8;
    const short* brow3 = Of + (pbase + 48 + lr) * 256 + lg * 8;
    f32x4 acc0 = {0,0,0,0}, acc1 = {0,0,0,0}, acc2 = {0,0,0,0}, acc3 = {0,0,0,0};
    #pragma unroll
    for (int ks = 0; ks < 8; ks++) {
        bf16x8 a = *(const bf16x8*)(arow + ks * 32);
        acc0 = MFMA(a, *(const bf16x8*)(brow0 + ks * 32), acc0);
        acc1 = MFMA(a, *(const bf16x8*)(brow1 + ks * 32), acc1);
        acc2 = MFMA(a, *(const bf16x8*)(brow2 + ks * 32), acc2);
        acc3 = MFMA(a, *(const bf16x8*)(brow3 + ks * 32), acc3);
    }
    f32x4 accs[4] = {acc0, acc1, acc2, acc3};
    #pragma unroll
    for (int i = 0; i < 4; i++) {
        int o = obase + 4 * lg + i;
        float b = bo[o];
        #pragma unroll
        for (int ct = 0; ct < 4; ct++) {
            int p = pbase + ct * 16 + lr;
            out[o * 2304 + p] = accs[ct][i] + b;
        }
    }
}

extern "C" void kernel_launch(void* const* d_in, const int* in_sizes, int n_in,
                              void* d_out, int out_size, void* d_ws, size_t ws_size,
                              hipStream_t stream) {
    const float* x  = (const float*)d_in[0];
    const float* Wq = (const float*)d_in[1];
    const float* bq = (const float*)d_in[2];
    const float* Wk = (const float*)d_in[3];
    const float* bk = (const float*)d_in[4];
    const float* Wv = (const float*)d_in[5];
    const float* bv = (const float*)d_in[6];
    const float* Wo = (const float*)d_in[7];
    const float* bo = (const float*)d_in[8];

    char* ws = (char*)d_ws;
    short* Wall = (short*)(ws);                     // 1024*256*2 = 524288 B
    short* xt   = (short*)(ws + 524288);            // 2304*256*2
    short* Qf   = (short*)(ws + 1703936);           // 9216*64*2
    short* Kf   = (short*)(ws + 2883584);           // 9216*64*2
    short* Vt   = (short*)(ws + 4063232);           // 64*9216*2
    short* Of   = (short*)(ws + 5242880);           // 2304*256*2 (ends 6422528)
    float* pm   = (float*)(ws + 6422528);           // 8*576*16*4 = 294912 max
    float* ps   = (float*)(ws + 6717440);           // 294912 max
    float* pacc = (float*)(ws + 7012352);           // nsplit*576*1024*4
    float* out  = (float*)d_out;

    // nsplit=8 needs ws end ~25.9MB; fall back to 4 (16.4MB) if ws is small
    int nsplit = (ws_size >= (size_t)7012352 + 8u * 2359296u) ? 8 : 4;
    int keysPer = 9216 / nsplit;
    int ntiles = keysPer / 64;

    k_prep<<<1168, 256, 0, stream>>>(x, Wq, Wk, Wv, Wo, Wall, xt);
    k_gemm_qkv<<<dim3(12, 36), 256, 0, stream>>>(Wall, xt, bq, bk, bv, Qf, Kf, Vt);
    k_attn<<<dim3(144, nsplit), 256, 0, stream>>>(Qf, Kf, Vt, keysPer, ntiles, pm, ps, pacc);
    k_attn_combine<<<576, 256, 0, stream>>>(pm, ps, pacc, Of, nsplit);
    k_gemm_out<<<dim3(4, 36), 256, 0, stream>>>(Wall + 768 * 256, Of, bo, out);
}